// Round 1
// baseline (3478.623 us; speedup 1.0000x reference)
//
#include <hip/hip_runtime.h>
#include <hip/hip_bf16.h>

// Problem constants
constexpr int N_  = 32;
constexpr int C_  = 256;
constexpr int K_  = 256;
constexpr int H_  = 56;
constexpr int W_  = 56;
constexpr int NW_ = K_ * C_ * 9;       // 589824 weight elements
constexpr int W4_ = W_ / 4;            // 14
constexpr int SP_ = H_ * W4_;          // 784 spatial positions per (n)
constexpr int KPT = 4;                 // output channels per thread
constexpr int KG  = K_ / KPT;          // 64 k-groups

// ws float layout:
//  [0] = sum|w|   [1] = masked sum   [2] = count
//  [4 .. 260)   partials pass 1 (256)
//  [260 .. 516) partials pass 2 sum (256)
//  [516 .. 772) partials pass 2 cnt (256)
//  byte offset 4096: ternarized weights (NW_ floats)
constexpr int WS_P1 = 4;
constexpr int WS_P2 = 260;
constexpr int WS_P3 = 516;
constexpr size_t WS_TW_BYTE_OFF = 4096;

__device__ inline float block_reduce_to_t0(float v, float* sm) {
    // wave64 butterfly-down then cross-wave via LDS; result valid in thread 0
    #pragma unroll
    for (int off = 32; off > 0; off >>= 1) v += __shfl_down(v, off, 64);
    const int wid = threadIdx.x >> 6, lane = threadIdx.x & 63;
    if (lane == 0) sm[wid] = v;
    __syncthreads();
    float s = 0.f;
    if (threadIdx.x == 0) {
        const int nw = (int)(blockDim.x >> 6);
        for (int i = 0; i < nw; ++i) s += sm[i];
    }
    return s;
}

__global__ void k_partial_abs(const float* __restrict__ w, float* __restrict__ ws) {
    __shared__ float sm[4];
    float s = 0.f;
    for (int i = blockIdx.x * blockDim.x + threadIdx.x; i < NW_; i += gridDim.x * blockDim.x)
        s += fabsf(w[i]);
    float r = block_reduce_to_t0(s, sm);
    if (threadIdx.x == 0) ws[WS_P1 + blockIdx.x] = r;
}

__global__ void k_final_abs(float* __restrict__ ws) {
    __shared__ float sm[4];
    float v = ws[WS_P1 + threadIdx.x];   // blockDim == 256 == #partials
    float r = block_reduce_to_t0(v, sm);
    if (threadIdx.x == 0) ws[0] = r;
}

__global__ void k_partial_masked(const float* __restrict__ w, float* __restrict__ ws) {
    __shared__ float sm1[4];
    __shared__ float sm2[4];
    const float thr = 0.75f * ws[0] / (float)NW_;
    float s = 0.f, c = 0.f;
    for (int i = blockIdx.x * blockDim.x + threadIdx.x; i < NW_; i += gridDim.x * blockDim.x) {
        float a = fabsf(w[i]);
        if (a > thr) { s += a; c += 1.f; }
    }
    #pragma unroll
    for (int off = 32; off > 0; off >>= 1) {
        s += __shfl_down(s, off, 64);
        c += __shfl_down(c, off, 64);
    }
    const int wid = threadIdx.x >> 6, lane = threadIdx.x & 63;
    if (lane == 0) { sm1[wid] = s; sm2[wid] = c; }
    __syncthreads();
    if (threadIdx.x == 0) {
        float S = 0.f, C2 = 0.f;
        for (int i = 0; i < 4; ++i) { S += sm1[i]; C2 += sm2[i]; }
        ws[WS_P2 + blockIdx.x] = S;
        ws[WS_P3 + blockIdx.x] = C2;
    }
}

__global__ void k_final_masked(float* __restrict__ ws) {
    __shared__ float sm1[4];
    __shared__ float sm2[4];
    float s = ws[WS_P2 + threadIdx.x];
    float c = ws[WS_P3 + threadIdx.x];
    #pragma unroll
    for (int off = 32; off > 0; off >>= 1) {
        s += __shfl_down(s, off, 64);
        c += __shfl_down(c, off, 64);
    }
    const int wid = threadIdx.x >> 6, lane = threadIdx.x & 63;
    if (lane == 0) { sm1[wid] = s; sm2[wid] = c; }
    __syncthreads();
    if (threadIdx.x == 0) {
        float S = 0.f, C2 = 0.f;
        for (int i = 0; i < 4; ++i) { S += sm1[i]; C2 += sm2[i]; }
        ws[1] = S;
        ws[2] = C2;
    }
}

__global__ void k_ternarize(const float* __restrict__ w, const float* __restrict__ wsc,
                            float* __restrict__ tw) {
    int i = blockIdx.x * blockDim.x + threadIdx.x;
    if (i >= NW_) return;
    const float thr = 0.75f * wsc[0] / (float)NW_;
    const float cnt = wsc[2];
    const float alpha = cnt > 0.f ? wsc[1] / fmaxf(cnt, 1.f) : 1.0f;
    float v = w[i];
    tw[i] = v > thr ? alpha : (v < -thr ? -alpha : 0.f);
}

// Direct conv. Block = (kg, n). Thread: up to 4 spatial positions; per position
// computes KPT k-channels x 4 consecutive output columns. Weights are
// block-uniform -> scalar loads; x loads: aligned float4 + 2 halo scalars.
template <bool OTF>
__global__ __launch_bounds__(256) void conv_tern(const float* __restrict__ x,
                                                 const float* __restrict__ wt,
                                                 const float* __restrict__ wsc,
                                                 float* __restrict__ out) {
    const int kg = blockIdx.x;
    const int n  = blockIdx.y;
    const int k0 = kg * KPT;

    float thr = 0.f, alpha = 0.f;
    if (OTF) {
        thr = 0.75f * wsc[0] / (float)NW_;
        const float cnt = wsc[2];
        alpha = cnt > 0.f ? wsc[1] / fmaxf(cnt, 1.f) : 1.0f;
    }

    for (int j = 0; j < 4; ++j) {
        const int sp = (int)threadIdx.x + j * 256;
        if (sp >= SP_) break;
        const int h  = sp / W4_;
        const int w0 = (sp % W4_) * 4;

        float acc[KPT][4];
        #pragma unroll
        for (int kt = 0; kt < KPT; ++kt)
            #pragma unroll
            for (int jj = 0; jj < 4; ++jj) acc[kt][jj] = 0.f;

        for (int c = 0; c < C_; ++c) {
            const float* xp = x + (((size_t)n * C_ + c) * H_) * W_;
            float xr[3][6];
            #pragma unroll
            for (int r = 0; r < 3; ++r) {
                const int hh = h + r - 1;
                const bool hv = (unsigned)hh < (unsigned)H_;
                const float* rowp = xp + hh * W_;
                if (hv) {
                    const float4 mid = *(const float4*)(rowp + w0);
                    xr[r][1] = mid.x; xr[r][2] = mid.y; xr[r][3] = mid.z; xr[r][4] = mid.w;
                    xr[r][0] = (w0 > 0)        ? rowp[w0 - 1] : 0.f;
                    xr[r][5] = (w0 + 4 < W_)   ? rowp[w0 + 4] : 0.f;
                } else {
                    #pragma unroll
                    for (int q = 0; q < 6; ++q) xr[r][q] = 0.f;
                }
            }
            #pragma unroll
            for (int kt = 0; kt < KPT; ++kt) {
                const float* wp = wt + ((size_t)(k0 + kt) * C_ + c) * 9;
                #pragma unroll
                for (int r = 0; r < 3; ++r) {
                    #pragma unroll
                    for (int s = 0; s < 3; ++s) {
                        float wv = wp[r * 3 + s];
                        if (OTF) wv = wv > thr ? alpha : (wv < -thr ? -alpha : 0.f);
                        #pragma unroll
                        for (int jj = 0; jj < 4; ++jj)
                            acc[kt][jj] = fmaf(wv, xr[r][jj + s], acc[kt][jj]);
                    }
                }
            }
        }

        #pragma unroll
        for (int kt = 0; kt < KPT; ++kt) {
            float4 o;
            o.x = acc[kt][0]; o.y = acc[kt][1]; o.z = acc[kt][2]; o.w = acc[kt][3];
            *(float4*)(out + ((((size_t)n * K_ + (k0 + kt)) * H_ + h) * W_ + w0)) = o;
        }
    }
}

extern "C" void kernel_launch(void* const* d_in, const int* in_sizes, int n_in,
                              void* d_out, int out_size, void* d_ws, size_t ws_size,
                              hipStream_t stream) {
    const float* x = (const float*)d_in[0];
    const float* w = (const float*)d_in[1];
    float* out = (float*)d_out;
    float* ws  = (float*)d_ws;
    float* tw  = (float*)((char*)d_ws + WS_TW_BYTE_OFF);

    // Deterministic two-stage reductions for threshold/alpha (no atomics ->
    // bit-identical every call, replay-safe).
    k_partial_abs<<<256, 256, 0, stream>>>(w, ws);
    k_final_abs<<<1, 256, 0, stream>>>(ws);
    k_partial_masked<<<256, 256, 0, stream>>>(w, ws);
    k_final_masked<<<1, 256, 0, stream>>>(ws);

    const bool materialize = ws_size >= WS_TW_BYTE_OFF + sizeof(float) * (size_t)NW_;
    dim3 grid(KG, N_);
    if (materialize) {
        k_ternarize<<<(NW_ + 255) / 256, 256, 0, stream>>>(w, ws, tw);
        conv_tern<false><<<grid, 256, 0, stream>>>(x, tw, ws, out);
    } else {
        conv_tern<true><<<grid, 256, 0, stream>>>(x, w, ws, out);
    }
}

// Round 2
// 321.683 us; speedup vs baseline: 10.8138x; 10.8138x over previous
//
#include <hip/hip_runtime.h>
#include <hip/hip_bf16.h>

typedef short short8 __attribute__((ext_vector_type(8)));
typedef float f32x4 __attribute__((ext_vector_type(4)));

constexpr int N_  = 32;
constexpr int C_  = 256;
constexpr int K_  = 256;
constexpr int H_  = 56;
constexpr int W_  = 56;
constexpr int HW_ = H_ * W_;           // 3136
constexpr int NW_ = K_ * C_ * 9;       // 589824

// ws float layout: [0]=sum|w| [1]=masked sum [2]=count, partials at [4..772)
constexpr int WS_P1 = 4;
constexpr int WS_P2 = 260;
constexpr int WS_P3 = 516;
constexpr size_t WS_WQ_BYTE_OFF = 4096;            // quantized sign weights (bf16)
constexpr size_t WS_NEEDED = WS_WQ_BYTE_OFF + (size_t)NW_ * 2;

// ---------------- deterministic reductions (threshold / alpha) ----------------
__device__ inline float block_reduce_to_t0(float v, float* sm) {
    #pragma unroll
    for (int off = 32; off > 0; off >>= 1) v += __shfl_down(v, off, 64);
    const int wid = threadIdx.x >> 6, lane = threadIdx.x & 63;
    if (lane == 0) sm[wid] = v;
    __syncthreads();
    float s = 0.f;
    if (threadIdx.x == 0) {
        const int nw = (int)(blockDim.x >> 6);
        for (int i = 0; i < nw; ++i) s += sm[i];
    }
    return s;
}

__global__ void k_partial_abs(const float* __restrict__ w, float* __restrict__ ws) {
    __shared__ float sm[4];
    float s = 0.f;
    for (int i = blockIdx.x * blockDim.x + threadIdx.x; i < NW_; i += gridDim.x * blockDim.x)
        s += fabsf(w[i]);
    float r = block_reduce_to_t0(s, sm);
    if (threadIdx.x == 0) ws[WS_P1 + blockIdx.x] = r;
}

__global__ void k_final_abs(float* __restrict__ ws) {
    __shared__ float sm[4];
    float v = ws[WS_P1 + threadIdx.x];
    float r = block_reduce_to_t0(v, sm);
    if (threadIdx.x == 0) ws[0] = r;
}

__global__ void k_partial_masked(const float* __restrict__ w, float* __restrict__ ws) {
    __shared__ float sm1[4];
    __shared__ float sm2[4];
    const float thr = 0.75f * ws[0] / (float)NW_;
    float s = 0.f, c = 0.f;
    for (int i = blockIdx.x * blockDim.x + threadIdx.x; i < NW_; i += gridDim.x * blockDim.x) {
        float a = fabsf(w[i]);
        if (a > thr) { s += a; c += 1.f; }
    }
    #pragma unroll
    for (int off = 32; off > 0; off >>= 1) {
        s += __shfl_down(s, off, 64);
        c += __shfl_down(c, off, 64);
    }
    const int wid = threadIdx.x >> 6, lane = threadIdx.x & 63;
    if (lane == 0) { sm1[wid] = s; sm2[wid] = c; }
    __syncthreads();
    if (threadIdx.x == 0) {
        float S = 0.f, C2 = 0.f;
        for (int i = 0; i < 4; ++i) { S += sm1[i]; C2 += sm2[i]; }
        ws[WS_P2 + blockIdx.x] = S;
        ws[WS_P3 + blockIdx.x] = C2;
    }
}

__global__ void k_final_masked(float* __restrict__ ws) {
    __shared__ float sm1[4];
    __shared__ float sm2[4];
    float s = ws[WS_P2 + threadIdx.x];
    float c = ws[WS_P3 + threadIdx.x];
    #pragma unroll
    for (int off = 32; off > 0; off >>= 1) {
        s += __shfl_down(s, off, 64);
        c += __shfl_down(c, off, 64);
    }
    const int wid = threadIdx.x >> 6, lane = threadIdx.x & 63;
    if (lane == 0) { sm1[wid] = s; sm2[wid] = c; }
    __syncthreads();
    if (threadIdx.x == 0) {
        float S = 0.f, C2 = 0.f;
        for (int i = 0; i < 4; ++i) { S += sm1[i]; C2 += sm2[i]; }
        ws[1] = S;
        ws[2] = C2;
    }
}

// ---------------- weight quantization: sign in bf16, K-step-major layout ----------------
// wq element index: ((rs*8 + c/32)*256 + k)*32 + (c%32), value in {+1, -1, 0} as bf16 bits.
__global__ void k_quant(const float* __restrict__ w, const float* __restrict__ wsc,
                        unsigned short* __restrict__ wq) {
    int i = blockIdx.x * 256 + threadIdx.x;
    if (i >= NW_) return;
    const float thr = 0.75f * wsc[0] / (float)NW_;
    float v = w[i];
    unsigned short q = v > thr ? (unsigned short)0x3F80
                               : (v < -thr ? (unsigned short)0xBF80 : (unsigned short)0);
    int k   = i / 2304;
    int rem = i - k * 2304;
    int c   = rem / 9;
    int rs  = rem - c * 9;               // r*3+s
    wq[((((rs << 3) + (c >> 5)) * 256 + k) << 5) + (c & 31)] = q;
}

// ---------------- MFMA conv ----------------
// Block: spatial 8x8 tile (+1 halo each side -> 10x10), all 256 output channels, one n.
// LDS: B = x tile bf16 [pos(100)][c(256)] rows padded to 528B; A = weights double-buffered,
//      per K-step 256k x 32c bf16, rows padded to 80B.
constexpr int BSTR  = 528;
constexpr int BLDS  = 100 * BSTR;        // 52800
constexpr int AOFF  = BLDS;
constexpr int ABUF  = 256 * 80;          // 20480
constexpr int LDSB  = AOFF + 2 * ABUF;   // 93760
constexpr int NSTEP = 72;                // 9 rs * 8 chunks

__device__ inline unsigned f2bf(float f) {   // RNE fp32->bf16 (bits), inputs are finite
    unsigned u = __builtin_bit_cast(unsigned, f);
    return (u + 0x7FFFu + ((u >> 16) & 1u)) >> 16;
}

__global__ __launch_bounds__(512) void conv_mfma(const float* __restrict__ x,
                                                 const unsigned short* __restrict__ wq,
                                                 const float* __restrict__ wsc,
                                                 float* __restrict__ out) {
    extern __shared__ char lds[];
    const int tid  = threadIdx.x;
    const int lane = tid & 63, wid = tid >> 6;
    const int wm = wid & 3, wn = wid >> 2;       // 4 m-waves x 2 n-waves
    const int lr = lane & 15, lg = lane >> 4;
    const int tile = blockIdx.x, n = blockIdx.y;
    const int ty = tile / 7, tx = tile - ty * 7;
    const int h0 = ty * 8, w0 = tx * 8;

    // ---- stage B: x halo tile -> bf16 LDS [pos][c], conflict-free b32 writes ----
    {
        const float* xn = x + (size_t)n * C_ * HW_;
        #pragma unroll
        for (int it = 0; it < 25; ++it) {
            int u  = tid + it * 512;
            int cp = u & 127;                 // channel pair (c = 2cp, 2cp+1)
            int p  = u >> 7;                  // halo position 0..99
            int yy = p / 10;
            int xx = p - yy * 10;
            int h = h0 - 1 + yy, w = w0 - 1 + xx;
            float v0 = 0.f, v1 = 0.f;
            if ((unsigned)h < (unsigned)H_ && (unsigned)w < (unsigned)W_) {
                const float* px = xn + (size_t)(2 * cp) * HW_ + h * W_ + w;
                v0 = px[0];
                v1 = px[HW_];
            }
            *(unsigned*)(lds + p * BSTR + cp * 4) = f2bf(v0) | (f2bf(v1) << 16);
        }
    }

    // fragment base byte-offsets
    int aB[4], bB[2], py[2], pxs[2];
    #pragma unroll
    for (int mf = 0; mf < 4; ++mf)
        aB[mf] = AOFF + (wm * 64 + mf * 16 + lr) * 80 + lg * 16;
    #pragma unroll
    for (int nf = 0; nf < 2; ++nf) {
        int pos = wn * 32 + nf * 16 + lr;     // 0..63 within 8x8 tile
        int y = pos >> 3, xq = pos & 7;
        py[nf] = y; pxs[nf] = xq;
        bB[nf] = (y * 10 + xq) * BSTR + lg * 16;
    }

    f32x4 acc[4][2] = {};

    const char* wqc = (const char*)wq;
    uint4 ar0, ar1;
    // stage A step 0 into buffer 0
    {
        ar0 = *(const uint4*)(wqc + (size_t)tid * 32);
        ar1 = *(const uint4*)(wqc + (size_t)tid * 32 + 16);
        char* dst = lds + AOFF + (tid >> 1) * 80 + (tid & 1) * 32;
        *(uint4*)dst = ar0;
        *(uint4*)(dst + 16) = ar1;
    }

    for (int rs = 0; rs < 9; ++rs) {
        const int r = rs / 3;
        const int roff = (r * 10 + (rs - r * 3)) * BSTR;   // shifted-row byte offset
        #pragma unroll
        for (int chi = 0; chi < 8; ++chi) {
            const int step = rs * 8 + chi;
            const int cur  = chi & 1;                       // rs*8 is even
            if (step + 1 < NSTEP) {                         // prefetch next A tile
                size_t off = (size_t)(step + 1) * 16384 + (size_t)tid * 32;
                ar0 = *(const uint4*)(wqc + off);
                ar1 = *(const uint4*)(wqc + off + 16);
            }
            __syncthreads();                                // buf(cur) ready; prev readers done
            short8 bfr[2], afr[4];
            #pragma unroll
            for (int nf = 0; nf < 2; ++nf)
                bfr[nf] = *(const short8*)(lds + bB[nf] + roff + chi * 64);
            #pragma unroll
            for (int mf = 0; mf < 4; ++mf)
                afr[mf] = *(const short8*)(lds + aB[mf] + cur * ABUF);
            #pragma unroll
            for (int mf = 0; mf < 4; ++mf)
                #pragma unroll
                for (int nf = 0; nf < 2; ++nf)
                    acc[mf][nf] = __builtin_amdgcn_mfma_f32_16x16x32_bf16(
                        afr[mf], bfr[nf], acc[mf][nf], 0, 0, 0);
            if (step + 1 < NSTEP) {                         // write next A tile to other buffer
                char* dst = lds + AOFF + (cur ^ 1) * ABUF + (tid >> 1) * 80 + (tid & 1) * 32;
                *(uint4*)dst = ar0;
                *(uint4*)(dst + 16) = ar1;
            }
        }
    }

    // ---- epilogue: scale by alpha, store fp32 ----
    const float cntv = wsc[2];
    const float alpha = cntv > 0.f ? wsc[1] / fmaxf(cntv, 1.f) : 1.0f;
    #pragma unroll
    for (int mf = 0; mf < 4; ++mf) {
        const int k = wm * 64 + mf * 16 + lg * 4;
        #pragma unroll
        for (int nf = 0; nf < 2; ++nf) {
            float* po = out + (((size_t)n * K_ + k) * H_ + (h0 + py[nf])) * W_ + (w0 + pxs[nf]);
            #pragma unroll
            for (int j = 0; j < 4; ++j)
                po[j * HW_] = alpha * acc[mf][nf][j];
        }
    }
}

// ---------------- fallback direct conv (small-ws path), from round 0 ----------------
constexpr int W4_ = W_ / 4;
constexpr int SP_ = H_ * W4_;
__global__ __launch_bounds__(256) void conv_tern_otf(const float* __restrict__ x,
                                                     const float* __restrict__ wt,
                                                     const float* __restrict__ wsc,
                                                     float* __restrict__ out) {
    const int kg = blockIdx.x;
    const int n  = blockIdx.y;
    const int k0 = kg * 4;
    const float thr = 0.75f * wsc[0] / (float)NW_;
    const float cnt = wsc[2];
    const float alpha = cnt > 0.f ? wsc[1] / fmaxf(cnt, 1.f) : 1.0f;
    for (int j = 0; j < 4; ++j) {
        const int sp = (int)threadIdx.x + j * 256;
        if (sp >= SP_) break;
        const int h  = sp / W4_;
        const int w0 = (sp % W4_) * 4;
        float acc[4][4];
        #pragma unroll
        for (int kt = 0; kt < 4; ++kt)
            #pragma unroll
            for (int jj = 0; jj < 4; ++jj) acc[kt][jj] = 0.f;
        for (int c = 0; c < C_; ++c) {
            const float* xp = x + (((size_t)n * C_ + c) * H_) * W_;
            float xr[3][6];
            #pragma unroll
            for (int r = 0; r < 3; ++r) {
                const int hh = h + r - 1;
                const bool hv = (unsigned)hh < (unsigned)H_;
                const float* rowp = xp + hh * W_;
                if (hv) {
                    const float4 mid = *(const float4*)(rowp + w0);
                    xr[r][1] = mid.x; xr[r][2] = mid.y; xr[r][3] = mid.z; xr[r][4] = mid.w;
                    xr[r][0] = (w0 > 0)      ? rowp[w0 - 1] : 0.f;
                    xr[r][5] = (w0 + 4 < W_) ? rowp[w0 + 4] : 0.f;
                } else {
                    #pragma unroll
                    for (int q = 0; q < 6; ++q) xr[r][q] = 0.f;
                }
            }
            #pragma unroll
            for (int kt = 0; kt < 4; ++kt) {
                const float* wp = wt + ((size_t)(k0 + kt) * C_ + c) * 9;
                #pragma unroll
                for (int r = 0; r < 3; ++r)
                    #pragma unroll
                    for (int s = 0; s < 3; ++s) {
                        float wv = wp[r * 3 + s];
                        wv = wv > thr ? alpha : (wv < -thr ? -alpha : 0.f);
                        #pragma unroll
                        for (int jj = 0; jj < 4; ++jj)
                            acc[kt][jj] = fmaf(wv, xr[r][jj + s], acc[kt][jj]);
                    }
            }
        }
        #pragma unroll
        for (int kt = 0; kt < 4; ++kt) {
            float4 o;
            o.x = acc[kt][0]; o.y = acc[kt][1]; o.z = acc[kt][2]; o.w = acc[kt][3];
            *(float4*)(out + ((((size_t)n * K_ + (k0 + kt)) * H_ + h) * W_ + w0)) = o;
        }
    }
}

extern "C" void kernel_launch(void* const* d_in, const int* in_sizes, int n_in,
                              void* d_out, int out_size, void* d_ws, size_t ws_size,
                              hipStream_t stream) {
    const float* x = (const float*)d_in[0];
    const float* w = (const float*)d_in[1];
    float* out = (float*)d_out;
    float* ws  = (float*)d_ws;
    unsigned short* wq = (unsigned short*)((char*)d_ws + WS_WQ_BYTE_OFF);

    k_partial_abs<<<256, 256, 0, stream>>>(w, ws);
    k_final_abs<<<1, 256, 0, stream>>>(ws);
    k_partial_masked<<<256, 256, 0, stream>>>(w, ws);
    k_final_masked<<<1, 256, 0, stream>>>(ws);

    if (ws_size >= WS_NEEDED) {
        k_quant<<<(NW_ + 255) / 256, 256, 0, stream>>>(w, ws, wq);
        hipFuncSetAttribute((const void*)conv_mfma,
                            hipFuncAttributeMaxDynamicSharedMemorySize, LDSB);
        dim3 grid(49, 32);
        conv_mfma<<<grid, 512, LDSB, stream>>>(x, wq, ws, out);
    } else {
        dim3 grid(64, 32);
        conv_tern_otf<<<grid, 256, 0, stream>>>(x, w, ws, out);
    }
}

// Round 3
// 208.936 us; speedup vs baseline: 16.6492x; 1.5396x over previous
//
#include <hip/hip_runtime.h>
#include <hip/hip_bf16.h>

typedef short short8 __attribute__((ext_vector_type(8)));
typedef float f32x4 __attribute__((ext_vector_type(4)));

constexpr int N_  = 32;
constexpr int C_  = 256;
constexpr int K_  = 256;
constexpr int H_  = 56;
constexpr int W_  = 56;
constexpr int HW_ = H_ * W_;             // 3136
constexpr int NW_ = K_ * C_ * 9;         // 589824

constexpr int TH   = 4;                  // output rows per band
constexpr int NB   = 14;                 // bands
constexpr int HR   = 6, HC = 58;         // halo rows/cols
constexpr int NH   = HR * HC;            // 348 halo positions
constexpr int BROW = 80;                 // B LDS row stride (32c bf16 = 64B + 16 pad)
constexpr int BSZ  = NH * BROW;          // 27840
constexpr int AOFF = BSZ;
constexpr int ASTEP = 16384;             // 256k x 32c bf16
constexpr int LDSB = AOFF + 2 * ASTEP;   // 60608
constexpr int NSTEP = 72;                // 8 chunks x 9 rs
constexpr int NPAIR = 16 * NH;           // 5568 (c-pair, hidx) staging elems

constexpr int WS_P1 = 4, WS_P2 = 260, WS_P3 = 516;
constexpr size_t WS_WQ = 4096;
constexpr size_t WS_NEEDED = WS_WQ + (size_t)NW_ * 2;

__device__ __forceinline__ unsigned f2bf(float f) {  // RNE fp32->bf16 bits
    unsigned u = __builtin_bit_cast(unsigned, f);
    return (u + 0x7FFFu + ((u >> 16) & 1u)) >> 16;
}

__device__ __forceinline__ void gll16(const void* g, void* l) {
    __builtin_amdgcn_global_load_lds(
        (const __attribute__((address_space(1))) unsigned int*)g,
        (__attribute__((address_space(3))) unsigned int*)l, 16, 0, 0);
}

// ---------------- reductions (deterministic, no atomics) ----------------
__global__ void k_abs_partial(const float* __restrict__ w, float* __restrict__ ws) {
    __shared__ float sm[4];
    float s = 0.f;
    for (int i = blockIdx.x * 256 + threadIdx.x; i < NW_; i += 256 * 256)
        s += fabsf(w[i]);
    #pragma unroll
    for (int o = 32; o > 0; o >>= 1) s += __shfl_down(s, o, 64);
    const int wid = threadIdx.x >> 6, lane = threadIdx.x & 63;
    if (lane == 0) sm[wid] = s;
    __syncthreads();
    if (threadIdx.x == 0) {
        float r = 0.f;
        for (int i = 0; i < 4; ++i) r += sm[i];
        ws[WS_P1 + blockIdx.x] = r;
    }
}

// 256 blocks x 256 thr: inline total of P1, write masked partials; blk0 writes ws[0]=total
__global__ void k_masked_partial(const float* __restrict__ w, float* __restrict__ ws) {
    __shared__ float sm[4];
    float t = ws[WS_P1 + threadIdx.x];
    #pragma unroll
    for (int o = 32; o > 0; o >>= 1) t += __shfl_down(t, o, 64);
    const int wid = threadIdx.x >> 6, lane = threadIdx.x & 63;
    if (lane == 0) sm[wid] = t;
    __syncthreads();
    float total = 0.f;
    for (int i = 0; i < 4; ++i) total += sm[i];
    const float thr = 0.75f * total / (float)NW_;
    if (blockIdx.x == 0 && threadIdx.x == 0) ws[0] = total;
    __syncthreads();
    float s = 0.f, c = 0.f;
    for (int i = blockIdx.x * 256 + threadIdx.x; i < NW_; i += 256 * 256) {
        float a = fabsf(w[i]);
        if (a > thr) { s += a; c += 1.f; }
    }
    #pragma unroll
    for (int o = 32; o > 0; o >>= 1) { s += __shfl_down(s, o, 64); c += __shfl_down(c, o, 64); }
    __shared__ float sm2[8];
    if (lane == 0) { sm2[wid] = s; sm2[wid + 4] = c; }
    __syncthreads();
    if (threadIdx.x == 0) {
        float S = 0.f, C2 = 0.f;
        for (int i = 0; i < 4; ++i) { S += sm2[i]; C2 += sm2[i + 4]; }
        ws[WS_P2 + blockIdx.x] = S;
        ws[WS_P3 + blockIdx.x] = C2;
    }
}

// fallback-only: reduce P2/P3 -> ws[1], ws[2]
__global__ void k_final_masked(float* __restrict__ ws) {
    __shared__ float sm[8];
    float s = ws[WS_P2 + threadIdx.x];
    float c = ws[WS_P3 + threadIdx.x];
    #pragma unroll
    for (int o = 32; o > 0; o >>= 1) { s += __shfl_down(s, o, 64); c += __shfl_down(c, o, 64); }
    const int wid = threadIdx.x >> 6, lane = threadIdx.x & 63;
    if (lane == 0) { sm[wid] = s; sm[wid + 4] = c; }
    __syncthreads();
    if (threadIdx.x == 0) {
        float S = 0.f, C2 = 0.f;
        for (int i = 0; i < 4; ++i) { S += sm[i]; C2 += sm[i + 4]; }
        ws[1] = S; ws[2] = C2;
    }
}

// 512-thread block reduce of a 256-float array in ws; every thread gets the sum
__device__ __forceinline__ float reduce256_all(const float* __restrict__ p, float* sm) {
    float v = threadIdx.x < 256 ? p[threadIdx.x] : 0.f;
    #pragma unroll
    for (int o = 32; o > 0; o >>= 1) v += __shfl_down(v, o, 64);
    const int wid = threadIdx.x >> 6, lane = threadIdx.x & 63;
    __syncthreads();
    if (lane == 0) sm[wid] = v;
    __syncthreads();
    float total = 0.f;
    #pragma unroll
    for (int i = 0; i < 8; ++i) total += sm[i];
    return total;
}

// quantize signs to bf16 {+1,-1,0} in [chi][rs][k][c32] layout; blk0 writes ws[3]=alpha
__global__ __launch_bounds__(512) void k_quant(const float* __restrict__ w,
                                               float* __restrict__ ws,
                                               unsigned short* __restrict__ wq) {
    __shared__ float sm[8];
    const float total = reduce256_all(ws + WS_P1, sm);
    const float msum  = reduce256_all(ws + WS_P2, sm);
    const float mcnt  = reduce256_all(ws + WS_P3, sm);
    const float thr = 0.75f * total / (float)NW_;
    const float alpha = mcnt > 0.f ? msum / fmaxf(mcnt, 1.f) : 1.0f;
    if (blockIdx.x == 0 && threadIdx.x == 0) ws[3] = alpha;
    const int i = blockIdx.x * 512 + threadIdx.x;
    if (i >= NW_) return;
    const float v = w[i];
    const unsigned short q = v > thr ? (unsigned short)0x3F80
                                     : (v < -thr ? (unsigned short)0xBF80 : (unsigned short)0);
    const int k   = i / 2304;
    const int rem = i - k * 2304;
    const int c   = rem / 9;
    const int rs  = rem - c * 9;
    const int chi = c >> 5;
    wq[(((chi * 9 + rs) * 256 + k) << 5) + (c & 31)] = q;
}

// ---------------- MFMA conv ----------------
// Block: 256k x 224pos (4 rows x 56 w), 8 waves = 4(k) x 2(pos).
// Wave: 64k x 112pos = 4 x 7 fragments of 16x16 (28 MFMA / 11 ds_read_b128 per step).
// B: x halo band (6x58) for one 32-channel chunk, rows 80B (conflict-free). Single buffer,
//    reg-staged with early load issue. A: sign weights via global_load_lds, double-buffered.
__global__ __launch_bounds__(512, 2) void conv_mfma(const float* __restrict__ x,
                                                    const unsigned short* __restrict__ wq,
                                                    const float* __restrict__ wsc,
                                                    float* __restrict__ out) {
    extern __shared__ char lds[];
    const int tid = threadIdx.x, lane = tid & 63, wid = tid >> 6;
    const int wm = wid & 3, wn = wid >> 2, lr = lane & 15, lg = lane >> 4;
    const int band = blockIdx.x, n = blockIdx.y;
    const int h0 = band * TH;

    int aB[4];
    #pragma unroll
    for (int mf = 0; mf < 4; ++mf) aB[mf] = AOFF + (wm * 64 + mf * 16 + lr) * 64 + lg * 16;
    int bB[7];
    #pragma unroll
    for (int nf = 0; nf < 7; ++nf) {
        const int pos = wn * 112 + nf * 16 + lr;
        const int y = pos / 56, xx = pos - y * 56;
        bB[nf] = (y * HC + xx) * BROW + lg * 16;
    }

    const float* xn = x + (size_t)n * C_ * HW_;
    const char*  wqc = (const char*)wq;

    f32x4 acc[4][7] = {};
    float sv0[11], sv1[11];

    // ---- prologue: stage B chunk 0 + A step 0 ----
    #pragma unroll
    for (int it = 0; it < 11; ++it) {
        const int u = it * 512 + tid;
        float a = 0.f, b = 0.f;
        if (u < NPAIR) {
            const int c2 = u / NH, hidx = u - c2 * NH;
            const int hy = hidx / HC, hx = hidx - hy * HC;
            const int h = h0 - 1 + hy, w = hx - 1;
            if ((unsigned)h < (unsigned)H_ && (unsigned)w < (unsigned)W_) {
                const float* p = xn + (size_t)(2 * c2) * HW_ + h * W_ + w;
                a = p[0]; b = p[HW_];
            }
        }
        sv0[it] = a; sv1[it] = b;
    }
    #pragma unroll
    for (int it = 0; it < 11; ++it) {
        const int u = it * 512 + tid;
        if (u < NPAIR) {
            const int c2 = u / NH, hidx = u - c2 * NH;
            *(unsigned*)(lds + hidx * BROW + c2 * 4) = f2bf(sv0[it]) | (f2bf(sv1[it]) << 16);
        }
    }
    {
        const char* g = wqc + (size_t)wid * 2048 + (size_t)lane * 16;
        char* l = lds + AOFF + wid * 2048;
        gll16(g, l);
        gll16(g + 1024, l + 1024);
    }

    // ---- main loop: 8 chunks x 9 rs steps ----
    for (int chi = 0; chi < 8; ++chi) {
        const int par = chi & 1;   // parity of step at rs=0 (9*chi ≡ chi mod 2)
        #pragma unroll
        for (int rs = 0; rs < 9; ++rs) {
            const int step = chi * 9 + rs;
            __syncthreads();   // A[cur] staged, B staged; prev writers/readers done

            short8 bfr[7], afr[4];
            const int rso = ((rs / 3) * HC + (rs % 3)) * BROW;
            #pragma unroll
            for (int nf = 0; nf < 7; ++nf)
                bfr[nf] = *(const short8*)(lds + bB[nf] + rso);
            const int asel = ((par ^ (rs & 1)) ? ASTEP : 0);
            #pragma unroll
            for (int mf = 0; mf < 4; ++mf)
                afr[mf] = *(const short8*)(lds + aB[mf] + asel);

            if (step + 1 < NSTEP) {   // prefetch next A tile into other buffer
                const char* g = wqc + (size_t)(step + 1) * ASTEP + (size_t)wid * 2048
                              + (size_t)lane * 16;
                char* l = lds + AOFF + (asel ^ ASTEP) + wid * 2048;
                gll16(g, l);
                gll16(g + 1024, l + 1024);
            }
            if (rs == 8 && chi < 7) {   // early-issue next-chunk B loads (latency under MFMA)
                const int c0 = (chi + 1) * 32;
                #pragma unroll
                for (int it = 0; it < 11; ++it) {
                    const int u = it * 512 + tid;
                    float a = 0.f, b = 0.f;
                    if (u < NPAIR) {
                        const int c2 = u / NH, hidx = u - c2 * NH;
                        const int hy = hidx / HC, hx = hidx - hy * HC;
                        const int h = h0 - 1 + hy, w = hx - 1;
                        if ((unsigned)h < (unsigned)H_ && (unsigned)w < (unsigned)W_) {
                            const float* p = xn + (size_t)(c0 + 2 * c2) * HW_ + h * W_ + w;
                            a = p[0]; b = p[HW_];
                        }
                    }
                    sv0[it] = a; sv1[it] = b;
                }
            }

            #pragma unroll
            for (int mf = 0; mf < 4; ++mf)
                #pragma unroll
                for (int nf = 0; nf < 7; ++nf)
                    acc[mf][nf] = __builtin_amdgcn_mfma_f32_16x16x32_bf16(
                        afr[mf], bfr[nf], acc[mf][nf], 0, 0, 0);
        }
        if (chi < 7) {   // write staged B chunk (single buffer; all readers are past it)
            __syncthreads();
            #pragma unroll
            for (int it = 0; it < 11; ++it) {
                const int u = it * 512 + tid;
                if (u < NPAIR) {
                    const int c2 = u / NH, hidx = u - c2 * NH;
                    *(unsigned*)(lds + hidx * BROW + c2 * 4) =
                        f2bf(sv0[it]) | (f2bf(sv1[it]) << 16);
                }
            }
        }
    }

    // ---- epilogue: alpha scale, contiguous-x stores ----
    const float alpha = wsc[3];
    #pragma unroll
    for (int mf = 0; mf < 4; ++mf) {
        const int k = wm * 64 + mf * 16 + lg * 4;
        #pragma unroll
        for (int nf = 0; nf < 7; ++nf) {
            const int pos = wn * 112 + nf * 16 + lr;
            const int y = pos / 56, xx = pos - y * 56;
            float* po = out + ((size_t)n * K_ + k) * HW_ + (h0 + y) * W_ + xx;
            #pragma unroll
            for (int j = 0; j < 4; ++j)
                po[(size_t)j * HW_] = alpha * acc[mf][nf][j];
        }
    }
}

// ---------------- fallback direct conv (tiny ws) ----------------
constexpr int W4_ = W_ / 4;
constexpr int SP_ = H_ * W4_;
__global__ __launch_bounds__(256) void conv_tern_otf(const float* __restrict__ x,
                                                     const float* __restrict__ wt,
                                                     const float* __restrict__ wsc,
                                                     float* __restrict__ out) {
    const int kg = blockIdx.x, n = blockIdx.y, k0 = kg * 4;
    const float thr = 0.75f * wsc[0] / (float)NW_;
    const float cnt = wsc[2];
    const float alpha = cnt > 0.f ? wsc[1] / fmaxf(cnt, 1.f) : 1.0f;
    for (int j = 0; j < 4; ++j) {
        const int sp = (int)threadIdx.x + j * 256;
        if (sp >= SP_) break;
        const int h = sp / W4_, w0 = (sp % W4_) * 4;
        float acc[4][4];
        #pragma unroll
        for (int kt = 0; kt < 4; ++kt)
            #pragma unroll
            for (int jj = 0; jj < 4; ++jj) acc[kt][jj] = 0.f;
        for (int c = 0; c < C_; ++c) {
            const float* xp = x + (((size_t)n * C_ + c) * H_) * W_;
            float xr[3][6];
            #pragma unroll
            for (int r = 0; r < 3; ++r) {
                const int hh = h + r - 1;
                const float* rowp = xp + hh * W_;
                if ((unsigned)hh < (unsigned)H_) {
                    const float4 mid = *(const float4*)(rowp + w0);
                    xr[r][1] = mid.x; xr[r][2] = mid.y; xr[r][3] = mid.z; xr[r][4] = mid.w;
                    xr[r][0] = (w0 > 0)      ? rowp[w0 - 1] : 0.f;
                    xr[r][5] = (w0 + 4 < W_) ? rowp[w0 + 4] : 0.f;
                } else {
                    #pragma unroll
                    for (int q = 0; q < 6; ++q) xr[r][q] = 0.f;
                }
            }
            #pragma unroll
            for (int kt = 0; kt < 4; ++kt) {
                const float* wp = wt + ((size_t)(k0 + kt) * C_ + c) * 9;
                #pragma unroll
                for (int r = 0; r < 3; ++r)
                    #pragma unroll
                    for (int s = 0; s < 3; ++s) {
                        float wv = wp[r * 3 + s];
                        wv = wv > thr ? alpha : (wv < -thr ? -alpha : 0.f);
                        #pragma unroll
                        for (int jj = 0; jj < 4; ++jj)
                            acc[kt][jj] = fmaf(wv, xr[r][jj + s], acc[kt][jj]);
                    }
            }
        }
        #pragma unroll
        for (int kt = 0; kt < 4; ++kt) {
            float4 o;
            o.x = acc[kt][0]; o.y = acc[kt][1]; o.z = acc[kt][2]; o.w = acc[kt][3];
            *(float4*)(out + ((((size_t)n * K_ + (k0 + kt)) * H_ + h) * W_ + w0)) = o;
        }
    }
}

extern "C" void kernel_launch(void* const* d_in, const int* in_sizes, int n_in,
                              void* d_out, int out_size, void* d_ws, size_t ws_size,
                              hipStream_t stream) {
    const float* x = (const float*)d_in[0];
    const float* w = (const float*)d_in[1];
    float* out = (float*)d_out;
    float* ws  = (float*)d_ws;
    unsigned short* wq = (unsigned short*)((char*)d_ws + WS_WQ);

    k_abs_partial<<<256, 256, 0, stream>>>(w, ws);
    k_masked_partial<<<256, 256, 0, stream>>>(w, ws);

    if (ws_size >= WS_NEEDED) {
        k_quant<<<(NW_ + 511) / 512, 512, 0, stream>>>(w, ws, wq);
        hipFuncSetAttribute((const void*)conv_mfma,
                            hipFuncAttributeMaxDynamicSharedMemorySize, LDSB);
        dim3 grid(NB, N_);
        conv_mfma<<<grid, 512, LDSB, stream>>>(x, wq, ws, out);
    } else {
        k_final_masked<<<1, 256, 0, stream>>>(ws);
        dim3 grid(64, N_);
        conv_tern_otf<<<grid, 256, 0, stream>>>(x, w, ws, out);
    }
}

// Round 4
// 192.295 us; speedup vs baseline: 18.0900x; 1.0865x over previous
//
#include <hip/hip_runtime.h>
#include <hip/hip_bf16.h>

typedef short short8 __attribute__((ext_vector_type(8)));
typedef float f32x4 __attribute__((ext_vector_type(4)));

constexpr int N_  = 32;
constexpr int C_  = 256;
constexpr int K_  = 256;
constexpr int H_  = 56;
constexpr int W_  = 56;
constexpr int HW_ = H_ * W_;             // 3136
constexpr int NW_ = K_ * C_ * 9;         // 589824

constexpr int TH   = 4;                  // output rows per band
constexpr int NB   = 14;                 // bands
constexpr int HR   = 6, HC = 58;         // halo rows/cols
constexpr int NH   = HR * HC;            // 348 halo positions
constexpr int BROW = 80;                 // B LDS row stride (32c bf16 = 64B + 16 pad)
constexpr int BSZ  = NH * BROW;          // 27840
constexpr int AOFF = BSZ;
constexpr int ASTEP = 16384;             // one step-tile: 256k x 32c bf16
constexpr int LDSB = AOFF + 3 * ASTEP;   // 76992 -> 2 blocks/CU
constexpr int NSTEP = 72;                // 8 chunks x 9 rs
constexpr int NPAIR = 16 * NH;           // 5568 (c-pair, hidx) staging elems

constexpr int WS_P1 = 4, WS_P2 = 260, WS_P3 = 516;
constexpr size_t WS_WQ = 4096;
constexpr size_t WS_NEEDED = WS_WQ + (size_t)NW_ * 2;

__device__ __forceinline__ unsigned f2bf(float f) {  // RNE fp32->bf16 bits
    unsigned u = __builtin_bit_cast(unsigned, f);
    return (u + 0x7FFFu + ((u >> 16) & 1u)) >> 16;
}

__device__ __forceinline__ void gll16(const void* g, void* l) {
    __builtin_amdgcn_global_load_lds(
        (const __attribute__((address_space(1))) unsigned int*)g,
        (__attribute__((address_space(3))) unsigned int*)l, 16, 0, 0);
}

// ---------------- reductions (deterministic, no atomics) ----------------
__global__ void k_abs_partial(const float* __restrict__ w, float* __restrict__ ws) {
    __shared__ float sm[4];
    float s = 0.f;
    for (int i = blockIdx.x * 256 + threadIdx.x; i < NW_; i += 256 * 256)
        s += fabsf(w[i]);
    #pragma unroll
    for (int o = 32; o > 0; o >>= 1) s += __shfl_down(s, o, 64);
    const int wid = threadIdx.x >> 6, lane = threadIdx.x & 63;
    if (lane == 0) sm[wid] = s;
    __syncthreads();
    if (threadIdx.x == 0) {
        float r = 0.f;
        for (int i = 0; i < 4; ++i) r += sm[i];
        ws[WS_P1 + blockIdx.x] = r;
    }
}

__global__ void k_masked_partial(const float* __restrict__ w, float* __restrict__ ws) {
    __shared__ float sm[4];
    float t = ws[WS_P1 + threadIdx.x];
    #pragma unroll
    for (int o = 32; o > 0; o >>= 1) t += __shfl_down(t, o, 64);
    const int wid = threadIdx.x >> 6, lane = threadIdx.x & 63;
    if (lane == 0) sm[wid] = t;
    __syncthreads();
    float total = 0.f;
    for (int i = 0; i < 4; ++i) total += sm[i];
    const float thr = 0.75f * total / (float)NW_;
    if (blockIdx.x == 0 && threadIdx.x == 0) ws[0] = total;
    __syncthreads();
    float s = 0.f, c = 0.f;
    for (int i = blockIdx.x * 256 + threadIdx.x; i < NW_; i += 256 * 256) {
        float a = fabsf(w[i]);
        if (a > thr) { s += a; c += 1.f; }
    }
    #pragma unroll
    for (int o = 32; o > 0; o >>= 1) { s += __shfl_down(s, o, 64); c += __shfl_down(c, o, 64); }
    __shared__ float sm2[8];
    if (lane == 0) { sm2[wid] = s; sm2[wid + 4] = c; }
    __syncthreads();
    if (threadIdx.x == 0) {
        float S = 0.f, C2 = 0.f;
        for (int i = 0; i < 4; ++i) { S += sm2[i]; C2 += sm2[i + 4]; }
        ws[WS_P2 + blockIdx.x] = S;
        ws[WS_P3 + blockIdx.x] = C2;
    }
}

__global__ void k_final_masked(float* __restrict__ ws) {
    __shared__ float sm[8];
    float s = ws[WS_P2 + threadIdx.x];
    float c = ws[WS_P3 + threadIdx.x];
    #pragma unroll
    for (int o = 32; o > 0; o >>= 1) { s += __shfl_down(s, o, 64); c += __shfl_down(c, o, 64); }
    const int wid = threadIdx.x >> 6, lane = threadIdx.x & 63;
    if (lane == 0) { sm[wid] = s; sm[wid + 4] = c; }
    __syncthreads();
    if (threadIdx.x == 0) {
        float S = 0.f, C2 = 0.f;
        for (int i = 0; i < 4; ++i) { S += sm[i]; C2 += sm[i + 4]; }
        ws[1] = S; ws[2] = C2;
    }
}

__device__ __forceinline__ float reduce256_all(const float* __restrict__ p, float* sm) {
    float v = threadIdx.x < 256 ? p[threadIdx.x] : 0.f;
    #pragma unroll
    for (int o = 32; o > 0; o >>= 1) v += __shfl_down(v, o, 64);
    const int wid = threadIdx.x >> 6, lane = threadIdx.x & 63;
    __syncthreads();
    if (lane == 0) sm[wid] = v;
    __syncthreads();
    float total = 0.f;
    #pragma unroll
    for (int i = 0; i < 8; ++i) total += sm[i];
    return total;
}

// quantize signs to bf16 {+1,-1,0} in swizzled [chi][rs][k][slot] layout.
// Within a 16KB step tile, element for (k, c5): e = (k<<5) | ((lg ^ ((k>>1)&3))<<3) | ci
// where lg = c5>>3, ci = c5&7. This makes the linear global_load_lds destination a
// bank-conflict-free layout for the 16x16x32 A-fragment ds_read_b128 (2-way max).
__global__ __launch_bounds__(512) void k_quant(const float* __restrict__ w,
                                               float* __restrict__ ws,
                                               unsigned short* __restrict__ wq) {
    __shared__ float sm[8];
    const float total = reduce256_all(ws + WS_P1, sm);
    const float msum  = reduce256_all(ws + WS_P2, sm);
    const float mcnt  = reduce256_all(ws + WS_P3, sm);
    const float thr = 0.75f * total / (float)NW_;
    const float alpha = mcnt > 0.f ? msum / fmaxf(mcnt, 1.f) : 1.0f;
    if (blockIdx.x == 0 && threadIdx.x == 0) ws[3] = alpha;
    const int i = blockIdx.x * 512 + threadIdx.x;
    if (i >= NW_) return;
    const float v = w[i];
    const unsigned short q = v > thr ? (unsigned short)0x3F80
                                     : (v < -thr ? (unsigned short)0xBF80 : (unsigned short)0);
    const int k   = i / 2304;
    const int rem = i - k * 2304;
    const int c   = rem / 9;
    const int rs  = rem - c * 9;
    const int chi = c >> 5, c5 = c & 31, lg = c5 >> 3, ci = c5 & 7;
    const int e   = (k << 5) | (((lg ^ ((k >> 1) & 3))) << 3) | ci;
    wq[(size_t)(chi * 9 + rs) * 8192 + e] = q;
}

// ---------------- MFMA conv ----------------
// Block: 256k x 224pos (4 rows x 56 w), 8 waves = 4(k) x 2(pos).
// Wave: 64k x 112pos = 4 x 7 fragments (28 MFMA / 11 ds_read_b128 per step).
// A: swizzled sign weights via global_load_lds, TRIPLE-buffered, prefetch depth 2,
//    per-step counted s_waitcnt vmcnt + raw s_barrier (loads stay in flight).
// B: x halo band (6x58) per 32-c chunk, rows 80B (2-way free); reg-staged at rs==7.
__global__ __launch_bounds__(512, 2) void conv_mfma(const float* __restrict__ x,
                                                    const unsigned short* __restrict__ wq,
                                                    const float* __restrict__ wsc,
                                                    float* __restrict__ out) {
    extern __shared__ char lds[];
    const int tid = threadIdx.x, lane = tid & 63, wid = tid >> 6;
    const int wm = wid & 3, wn = wid >> 2, lr = lane & 15, lg = lane >> 4;
    const int band = blockIdx.x, n = blockIdx.y;
    const int h0 = band * TH;

    // A fragment base offsets with the bank-swizzle baked in (k constant per mf)
    int aB[4];
    #pragma unroll
    for (int mf = 0; mf < 4; ++mf) {
        const int k = wm * 64 + mf * 16 + lr;
        aB[mf] = AOFF + k * 64 + ((lg ^ ((k >> 1) & 3)) << 4);
    }
    int bB[7];
    #pragma unroll
    for (int nf = 0; nf < 7; ++nf) {
        const int pos = wn * 112 + nf * 16 + lr;
        const int y = pos / 56, xx = pos - y * 56;
        bB[nf] = (y * HC + xx) * BROW + lg * 16;
    }

    const float* xn = x + (size_t)n * C_ * HW_;
    const char*  wqc = (const char*)wq;

    f32x4 acc[4][7] = {};
    float sv0[11], sv1[11];

    // ---- prologue: stage B chunk 0; issue A step 0 and 1 ----
    #pragma unroll
    for (int it = 0; it < 11; ++it) {
        const int u = it * 512 + tid;
        float a = 0.f, b = 0.f;
        if (u < NPAIR) {
            const int c2 = u / NH, hidx = u - c2 * NH;
            const int hy = hidx / HC, hx = hidx - hy * HC;
            const int h = h0 - 1 + hy, w = hx - 1;
            if ((unsigned)h < (unsigned)H_ && (unsigned)w < (unsigned)W_) {
                const float* p = xn + (size_t)(2 * c2) * HW_ + h * W_ + w;
                a = p[0]; b = p[HW_];
            }
        }
        sv0[it] = a; sv1[it] = b;
    }
    #pragma unroll
    for (int it = 0; it < 11; ++it) {
        const int u = it * 512 + tid;
        if (u < NPAIR) {
            const int c2 = u / NH, hidx = u - c2 * NH;
            *(unsigned*)(lds + hidx * BROW + c2 * 4) = f2bf(sv0[it]) | (f2bf(sv1[it]) << 16);
        }
    }
    {
        const char* g = wqc + (size_t)wid * 2048 + (size_t)lane * 16;
        char* l = lds + AOFF + wid * 2048 + 0 * ASTEP;      // step 0 -> buf 0
        gll16(g, l);
        gll16(g + 1024, l + 1024);
        const char* g1 = g + ASTEP;
        char* l1 = lds + AOFF + wid * 2048 + 1 * ASTEP;     // step 1 -> buf 1
        gll16(g1, l1);
        gll16(g1 + 1024, l1 + 1024);
    }

    // ---- main loop: 8 chunks x 9 rs steps, one raw barrier per step ----
    for (int chi = 0; chi < 8; ++chi) {
        #pragma unroll
        for (int rs = 0; rs < 9; ++rs) {
            const int step = chi * 9 + rs;
            // counted wait: keep newest prefetches in flight, drain only what's needed
            if (rs == 8) {
                if (chi < 7) asm volatile("s_waitcnt vmcnt(5) lgkmcnt(0)" ::: "memory");
                else         asm volatile("s_waitcnt vmcnt(0) lgkmcnt(0)" ::: "memory");
            } else {
                asm volatile("s_waitcnt vmcnt(2) lgkmcnt(0)" ::: "memory");
            }
            __builtin_amdgcn_s_barrier();

            short8 bfr[7], afr[4];
            const int rso  = ((rs / 3) * HC + (rs % 3)) * BROW;
            const int asel = (rs % 3) * ASTEP;                 // 9 % 3 == 0
            #pragma unroll
            for (int nf = 0; nf < 7; ++nf)
                bfr[nf] = *(const short8*)(lds + bB[nf] + rso);
            #pragma unroll
            for (int mf = 0; mf < 4; ++mf)
                afr[mf] = *(const short8*)(lds + aB[mf] + asel);

            if (step + 2 < NSTEP) {   // prefetch A[step+2] (depth 2)
                const char* g = wqc + (size_t)(step + 2) * ASTEP + (size_t)wid * 2048
                              + (size_t)lane * 16;
                char* l = lds + AOFF + ((rs + 2) % 3) * ASTEP + wid * 2048;
                gll16(g, l);
                gll16(g + 1024, l + 1024);
            }
            if (rs == 7 && chi < 7) {   // early-issue next-chunk B loads (2 steps of hiding)
                const int c0 = (chi + 1) * 32;
                #pragma unroll
                for (int it = 0; it < 11; ++it) {
                    const int u = it * 512 + tid;
                    float a = 0.f, b = 0.f;
                    if (u < NPAIR) {
                        const int c2 = u / NH, hidx = u - c2 * NH;
                        const int hy = hidx / HC, hx = hidx - hy * HC;
                        const int h = h0 - 1 + hy, w = hx - 1;
                        if ((unsigned)h < (unsigned)H_ && (unsigned)w < (unsigned)W_) {
                            const float* p = xn + (size_t)(c0 + 2 * c2) * HW_ + h * W_ + w;
                            a = p[0]; b = p[HW_];
                        }
                    }
                    sv0[it] = a; sv1[it] = b;
                }
            }

            __builtin_amdgcn_s_setprio(1);
            #pragma unroll
            for (int mf = 0; mf < 4; ++mf)
                #pragma unroll
                for (int nf = 0; nf < 7; ++nf)
                    acc[mf][nf] = __builtin_amdgcn_mfma_f32_16x16x32_bf16(
                        afr[mf], bfr[nf], acc[mf][nf], 0, 0, 0);
            __builtin_amdgcn_s_setprio(0);
        }
        if (chi < 7) {   // B buffer handoff: all readers past it, write staged regs
            __syncthreads();
            #pragma unroll
            for (int it = 0; it < 11; ++it) {
                const int u = it * 512 + tid;
                if (u < NPAIR) {
                    const int c2 = u / NH, hidx = u - c2 * NH;
                    *(unsigned*)(lds + hidx * BROW + c2 * 4) =
                        f2bf(sv0[it]) | (f2bf(sv1[it]) << 16);
                }
            }
        }
    }

    // ---- epilogue: alpha scale, contiguous-x stores ----
    const float alpha = wsc[3];
    #pragma unroll
    for (int mf = 0; mf < 4; ++mf) {
        const int k = wm * 64 + mf * 16 + lg * 4;
        #pragma unroll
        for (int nf = 0; nf < 7; ++nf) {
            const int pos = wn * 112 + nf * 16 + lr;
            const int y = pos / 56, xx = pos - y * 56;
            float* po = out + ((size_t)n * K_ + k) * HW_ + (h0 + y) * W_ + xx;
            #pragma unroll
            for (int j = 0; j < 4; ++j)
                po[(size_t)j * HW_] = alpha * acc[mf][nf][j];
        }
    }
}

// ---------------- fallback direct conv (tiny ws) ----------------
constexpr int W4_ = W_ / 4;
constexpr int SP_ = H_ * W4_;
__global__ __launch_bounds__(256) void conv_tern_otf(const float* __restrict__ x,
                                                     const float* __restrict__ wt,
                                                     const float* __restrict__ wsc,
                                                     float* __restrict__ out) {
    const int kg = blockIdx.x, n = blockIdx.y, k0 = kg * 4;
    const float thr = 0.75f * wsc[0] / (float)NW_;
    const float cnt = wsc[2];
    const float alpha = cnt > 0.f ? wsc[1] / fmaxf(cnt, 1.f) : 1.0f;
    for (int j = 0; j < 4; ++j) {
        const int sp = (int)threadIdx.x + j * 256;
        if (sp >= SP_) break;
        const int h = sp / W4_, w0 = (sp % W4_) * 4;
        float acc[4][4];
        #pragma unroll
        for (int kt = 0; kt < 4; ++kt)
            #pragma unroll
            for (int jj = 0; jj < 4; ++jj) acc[kt][jj] = 0.f;
        for (int c = 0; c < C_; ++c) {
            const float* xp = x + (((size_t)n * C_ + c) * H_) * W_;
            float xr[3][6];
            #pragma unroll
            for (int r = 0; r < 3; ++r) {
                const int hh = h + r - 1;
                const float* rowp = xp + hh * W_;
                if ((unsigned)hh < (unsigned)H_) {
                    const float4 mid = *(const float4*)(rowp + w0);
                    xr[r][1] = mid.x; xr[r][2] = mid.y; xr[r][3] = mid.z; xr[r][4] = mid.w;
                    xr[r][0] = (w0 > 0)      ? rowp[w0 - 1] : 0.f;
                    xr[r][5] = (w0 + 4 < W_) ? rowp[w0 + 4] : 0.f;
                } else {
                    #pragma unroll
                    for (int q = 0; q < 6; ++q) xr[r][q] = 0.f;
                }
            }
            #pragma unroll
            for (int kt = 0; kt < 4; ++kt) {
                const float* wp = wt + ((size_t)(k0 + kt) * C_ + c) * 9;
                #pragma unroll
                for (int r = 0; r < 3; ++r)
                    #pragma unroll
                    for (int s = 0; s < 3; ++s) {
                        float wv = wp[r * 3 + s];
                        wv = wv > thr ? alpha : (wv < -thr ? -alpha : 0.f);
                        #pragma unroll
                        for (int jj = 0; jj < 4; ++jj)
                            acc[kt][jj] = fmaf(wv, xr[r][jj + s], acc[kt][jj]);
                    }
            }
        }
        #pragma unroll
        for (int kt = 0; kt < 4; ++kt) {
            float4 o;
            o.x = acc[kt][0]; o.y = acc[kt][1]; o.z = acc[kt][2]; o.w = acc[kt][3];
            *(float4*)(out + ((((size_t)n * K_ + (k0 + kt)) * H_ + h) * W_ + w0)) = o;
        }
    }
}

extern "C" void kernel_launch(void* const* d_in, const int* in_sizes, int n_in,
                              void* d_out, int out_size, void* d_ws, size_t ws_size,
                              hipStream_t stream) {
    const float* x = (const float*)d_in[0];
    const float* w = (const float*)d_in[1];
    float* out = (float*)d_out;
    float* ws  = (float*)d_ws;
    unsigned short* wq = (unsigned short*)((char*)d_ws + WS_WQ);

    k_abs_partial<<<256, 256, 0, stream>>>(w, ws);
    k_masked_partial<<<256, 256, 0, stream>>>(w, ws);

    if (ws_size >= WS_NEEDED) {
        k_quant<<<(NW_ + 511) / 512, 512, 0, stream>>>(w, ws, wq);
        hipFuncSetAttribute((const void*)conv_mfma,
                            hipFuncAttributeMaxDynamicSharedMemorySize, LDSB);
        dim3 grid(NB, N_);
        conv_mfma<<<grid, 512, LDSB, stream>>>(x, wq, ws, out);
    } else {
        k_final_masked<<<1, 256, 0, stream>>>(ws);
        dim3 grid(64, N_);
        conv_tern_otf<<<grid, 256, 0, stream>>>(x, w, ws, out);
    }
}

// Round 5
// 128.877 us; speedup vs baseline: 26.9918x; 1.4921x over previous
//
#include <hip/hip_runtime.h>
#include <hip/hip_bf16.h>

typedef short short8 __attribute__((ext_vector_type(8)));
typedef float f32x4 __attribute__((ext_vector_type(4)));

constexpr int N_  = 32;
constexpr int C_  = 256;
constexpr int K_  = 256;
constexpr int H_  = 56;
constexpr int W_  = 56;
constexpr int HW_ = H_ * W_;             // 3136
constexpr int NW_ = K_ * C_ * 9;         // 589824

constexpr int TH   = 4;                  // output rows per band
constexpr int NB   = 14;                 // bands
constexpr int HR   = 6, HC = 58;         // halo rows/cols
constexpr int NH   = HR * HC;            // 348 halo positions
constexpr int BROW = 80;                 // B LDS row stride (32c bf16 = 64B + 16 pad)
constexpr int BSZ  = NH * BROW;          // 27840 per buffer
constexpr int NPAIR2 = 8 * NH;           // 2784 (c-quad, hidx) staging elems
constexpr int ASTEP  = 16384;            // one step-tile: 256k x 32c bf16

constexpr int WS_P1 = 4, WS_P2 = 260, WS_P3 = 516;
constexpr size_t WS_WQ = 4096;
constexpr size_t WS_NEEDED = WS_WQ + (size_t)NW_ * 2;

__device__ __forceinline__ unsigned f2bf(float f) {  // RNE fp32->bf16 bits
    unsigned u = __builtin_bit_cast(unsigned, f);
    return (u + 0x7FFFu + ((u >> 16) & 1u)) >> 16;
}

// ---------------- reductions (deterministic, no atomics) ----------------
__global__ void k_abs_partial(const float* __restrict__ w, float* __restrict__ ws) {
    __shared__ float sm[4];
    float s = 0.f;
    for (int i = blockIdx.x * 256 + threadIdx.x; i < NW_; i += 256 * 256)
        s += fabsf(w[i]);
    #pragma unroll
    for (int o = 32; o > 0; o >>= 1) s += __shfl_down(s, o, 64);
    const int wid = threadIdx.x >> 6, lane = threadIdx.x & 63;
    if (lane == 0) sm[wid] = s;
    __syncthreads();
    if (threadIdx.x == 0) {
        float r = 0.f;
        for (int i = 0; i < 4; ++i) r += sm[i];
        ws[WS_P1 + blockIdx.x] = r;
    }
}

__global__ void k_masked_partial(const float* __restrict__ w, float* __restrict__ ws) {
    __shared__ float sm[4];
    float t = ws[WS_P1 + threadIdx.x];
    #pragma unroll
    for (int o = 32; o > 0; o >>= 1) t += __shfl_down(t, o, 64);
    const int wid = threadIdx.x >> 6, lane = threadIdx.x & 63;
    if (lane == 0) sm[wid] = t;
    __syncthreads();
    float total = 0.f;
    for (int i = 0; i < 4; ++i) total += sm[i];
    const float thr = 0.75f * total / (float)NW_;
    if (blockIdx.x == 0 && threadIdx.x == 0) ws[0] = total;
    __syncthreads();
    float s = 0.f, c = 0.f;
    for (int i = blockIdx.x * 256 + threadIdx.x; i < NW_; i += 256 * 256) {
        float a = fabsf(w[i]);
        if (a > thr) { s += a; c += 1.f; }
    }
    #pragma unroll
    for (int o = 32; o > 0; o >>= 1) { s += __shfl_down(s, o, 64); c += __shfl_down(c, o, 64); }
    __shared__ float sm2[8];
    if (lane == 0) { sm2[wid] = s; sm2[wid + 4] = c; }
    __syncthreads();
    if (threadIdx.x == 0) {
        float S = 0.f, C2 = 0.f;
        for (int i = 0; i < 4; ++i) { S += sm2[i]; C2 += sm2[i + 4]; }
        ws[WS_P2 + blockIdx.x] = S;
        ws[WS_P3 + blockIdx.x] = C2;
    }
}

__global__ void k_final_masked(float* __restrict__ ws) {
    __shared__ float sm[8];
    float s = ws[WS_P2 + threadIdx.x];
    float c = ws[WS_P3 + threadIdx.x];
    #pragma unroll
    for (int o = 32; o > 0; o >>= 1) { s += __shfl_down(s, o, 64); c += __shfl_down(c, o, 64); }
    const int wid = threadIdx.x >> 6, lane = threadIdx.x & 63;
    if (lane == 0) { sm[wid] = s; sm[wid + 4] = c; }
    __syncthreads();
    if (threadIdx.x == 0) {
        float S = 0.f, C2 = 0.f;
        for (int i = 0; i < 4; ++i) { S += sm[i]; C2 += sm[i + 4]; }
        ws[1] = S; ws[2] = C2;
    }
}

__device__ __forceinline__ float reduce256_all(const float* __restrict__ p, float* sm) {
    float v = threadIdx.x < 256 ? p[threadIdx.x] : 0.f;
    #pragma unroll
    for (int o = 32; o > 0; o >>= 1) v += __shfl_down(v, o, 64);
    const int wid = threadIdx.x >> 6, lane = threadIdx.x & 63;
    __syncthreads();
    if (lane == 0) sm[wid] = v;
    __syncthreads();
    float total = 0.f;
    #pragma unroll
    for (int i = 0; i < 8; ++i) total += sm[i];
    return total;
}

// quantize signs to bf16 {+1,-1,0} in [step=(chi*9+rs)][k][c5] layout; blk0 writes ws[3]=alpha
__global__ __launch_bounds__(512) void k_quant(const float* __restrict__ w,
                                               float* __restrict__ ws,
                                               unsigned short* __restrict__ wq) {
    __shared__ float sm[8];
    const float total = reduce256_all(ws + WS_P1, sm);
    const float msum  = reduce256_all(ws + WS_P2, sm);
    const float mcnt  = reduce256_all(ws + WS_P3, sm);
    const float thr = 0.75f * total / (float)NW_;
    const float alpha = mcnt > 0.f ? msum / fmaxf(mcnt, 1.f) : 1.0f;
    if (blockIdx.x == 0 && threadIdx.x == 0) ws[3] = alpha;
    const int i = blockIdx.x * 512 + threadIdx.x;
    if (i >= NW_) return;
    const float v = w[i];
    const unsigned short q = v > thr ? (unsigned short)0x3F80
                                     : (v < -thr ? (unsigned short)0xBF80 : (unsigned short)0);
    const int k   = i / 2304;
    const int rem = i - k * 2304;
    const int c   = rem / 9;
    const int rs  = rem - c * 9;
    const int chi = c >> 5, c5 = c & 31;
    wq[(size_t)(chi * 9 + rs) * 8192 + (k << 5) + c5] = q;
}

// ---------------- MFMA conv: self-paced waves, barrier only per chunk ----------------
// Block: 256k x 224pos (4 rows x 56 w), 8 waves = 4(k) x 2(pos).
// Wave: 64k x 112pos = 4 x 7 fragments (28 MFMA per step).
// A: sign weights loaded DIRECTLY global->register per wave (L2-resident), depth-1
//    pipelined into parity-alternating reg pair; all waits are compiler register-dep
//    waitcnts -> no per-step barrier at all.
// B: x halo band (6x58) per 32-c chunk in LDS, DOUBLE-buffered; loads at rs==6,
//    b64 writes at rs==8, one raw barrier per chunk (8 total).
constexpr int RSO_[9] = {
    (0*HC+0)*BROW, (0*HC+1)*BROW, (0*HC+2)*BROW,
    (1*HC+0)*BROW, (1*HC+1)*BROW, (1*HC+2)*BROW,
    (2*HC+0)*BROW, (2*HC+1)*BROW, (2*HC+2)*BROW };

struct ConvState {
    const float* xn;
    const char*  wqc;
    char*        ldsp;
    size_t       aoff;      // per-lane byte offset within a step tile
    int          h0, tid;
    int          bB[7];     // per-lane B frag byte offsets within a buffer
};

__device__ __forceinline__ void load_a(short8 (&d)[4], const ConvState& st, int step) {
    const char* ap = st.wqc + (size_t)step * ASTEP + st.aoff;
    d[0] = *(const short8*)(ap);
    d[1] = *(const short8*)(ap + 1024);
    d[2] = *(const short8*)(ap + 2048);
    d[3] = *(const short8*)(ap + 3072);
}

__device__ __forceinline__ void issue_b(const ConvState& st, int c0,
                                        float (&bs)[6][4], unsigned& bmask) {
    bmask = 0;
    #pragma unroll
    for (int it = 0; it < 6; ++it) {
        const int u  = it * 512 + st.tid;
        const bool vu = u < NPAIR2;
        const int uu = vu ? u : 0;
        const int c4 = uu / NH, hidx = uu - c4 * NH;
        const int hy = hidx / HC, hx = hidx - hy * HC;
        const int h  = st.h0 - 1 + hy, w = hx - 1;
        const bool ok = vu && (unsigned)h < (unsigned)H_ && (unsigned)w < (unsigned)W_;
        const int off = ok ? ((c0 + 4 * c4) * HW_ + h * W_ + w) : 0;
        const float* p = st.xn + off;
        bs[it][0] = p[0];
        bs[it][1] = p[HW_];
        bs[it][2] = p[2 * HW_];
        bs[it][3] = p[3 * HW_];
        bmask |= (ok ? 1u : 0u) << it;
    }
}

__device__ __forceinline__ void write_b(const ConvState& st, int base,
                                        const float (&bs)[6][4], unsigned bmask) {
    #pragma unroll
    for (int it = 0; it < 6; ++it) {
        const int u = it * 512 + st.tid;
        if (u < NPAIR2) {
            const int c4 = u / NH, hidx = u - c4 * NH;
            const bool ok = (bmask >> it) & 1u;
            const float f0 = ok ? bs[it][0] : 0.f;
            const float f1 = ok ? bs[it][1] : 0.f;
            const float f2 = ok ? bs[it][2] : 0.f;
            const float f3 = ok ? bs[it][3] : 0.f;
            uint2 v;
            v.x = f2bf(f0) | (f2bf(f1) << 16);
            v.y = f2bf(f2) | (f2bf(f3) << 16);
            *(uint2*)(st.ldsp + base + hidx * BROW + c4 * 8) = v;
        }
    }
}

template <int PAR, bool LASTCH>
__device__ __forceinline__ void do_chunk(int chi, const ConvState& st,
                                         short8 (&afr)[2][4], f32x4 (&acc)[4][7],
                                         float (&bs)[6][4], unsigned& bmask) {
    const int rdbase = PAR * BSZ;
    #pragma unroll
    for (int rs = 0; rs < 9; ++rs) {
        const int cur = (PAR + rs) & 1, nxt = cur ^ 1;
        const int step = chi * 9 + rs;
        if (!(LASTCH && rs == 8))
            load_a(afr[nxt], st, step + 1);   // next step's A into the other reg set

        short8 bfr[7];
        #pragma unroll
        for (int nf = 0; nf < 7; ++nf)
            bfr[nf] = *(const short8*)(st.ldsp + rdbase + st.bB[nf] + RSO_[rs]);

        __builtin_amdgcn_s_setprio(1);
        #pragma unroll
        for (int nf = 0; nf < 7; ++nf)
            #pragma unroll
            for (int mf = 0; mf < 4; ++mf)
                acc[mf][nf] = __builtin_amdgcn_mfma_f32_16x16x32_bf16(
                    afr[cur][mf], bfr[nf], acc[mf][nf], 0, 0, 0);
        __builtin_amdgcn_s_setprio(0);

        if (rs == 6 && !LASTCH)
            issue_b(st, (chi + 1) * 32, bs, bmask);   // next chunk's x, 2 steps of latency
        if (rs == 8 && !LASTCH) {
            write_b(st, (PAR ^ 1) * BSZ, bs, bmask);
            asm volatile("s_waitcnt lgkmcnt(0)" ::: "memory");
            __builtin_amdgcn_s_barrier();             // only sync point: B buffer handoff
        }
    }
}

__global__ __launch_bounds__(512, 2) void conv_mfma(const float* __restrict__ x,
                                                    const unsigned short* __restrict__ wq,
                                                    const float* __restrict__ wsc,
                                                    float* __restrict__ out) {
    __shared__ char lds[2 * BSZ];
    const int tid = threadIdx.x, lane = tid & 63, wid = tid >> 6;
    const int wm = wid & 3, wn = wid >> 2, lr = lane & 15, lg = lane >> 4;
    const int band = blockIdx.x, n = blockIdx.y;

    ConvState st;
    st.xn   = x + (size_t)n * C_ * HW_;
    st.wqc  = (const char*)wq;
    st.ldsp = lds;
    st.aoff = (size_t)(wm * 64 + lr) * 64 + lg * 16;
    st.h0   = band * TH;
    st.tid  = tid;
    #pragma unroll
    for (int nf = 0; nf < 7; ++nf) {
        const int pos = wn * 112 + nf * 16 + lr;
        const int y = pos / 56, xx = pos - y * 56;
        st.bB[nf] = (y * HC + xx) * BROW + lg * 16;
    }

    f32x4 acc[4][7] = {};
    short8 afr[2][4];
    float bs[6][4];
    unsigned bmask;

    // prologue: B chunk 0 -> buf0; A step 0 -> afr[0]
    issue_b(st, 0, bs, bmask);
    load_a(afr[0], st, 0);
    write_b(st, 0, bs, bmask);
    asm volatile("s_waitcnt lgkmcnt(0)" ::: "memory");
    __builtin_amdgcn_s_barrier();

    for (int cc = 0; cc < 3; ++cc) {
        do_chunk<0, false>(2 * cc,     st, afr, acc, bs, bmask);
        do_chunk<1, false>(2 * cc + 1, st, afr, acc, bs, bmask);
    }
    do_chunk<0, false>(6, st, afr, acc, bs, bmask);
    do_chunk<1, true >(7, st, afr, acc, bs, bmask);

    // epilogue: alpha scale, contiguous-x stores
    const float alpha = wsc[3];
    #pragma unroll
    for (int mf = 0; mf < 4; ++mf) {
        const int k = wm * 64 + mf * 16 + lg * 4;
        #pragma unroll
        for (int nf = 0; nf < 7; ++nf) {
            const int pos = wn * 112 + nf * 16 + lr;
            const int y = pos / 56, xx = pos - y * 56;
            float* po = out + ((size_t)n * K_ + k) * HW_ + (st.h0 + y) * W_ + xx;
            #pragma unroll
            for (int j = 0; j < 4; ++j)
                po[(size_t)j * HW_] = alpha * acc[mf][nf][j];
        }
    }
}

// ---------------- fallback direct conv (tiny ws) ----------------
constexpr int W4_ = W_ / 4;
constexpr int SP_ = H_ * W4_;
__global__ __launch_bounds__(256) void conv_tern_otf(const float* __restrict__ x,
                                                     const float* __restrict__ wt,
                                                     const float* __restrict__ wsc,
                                                     float* __restrict__ out) {
    const int kg = blockIdx.x, n = blockIdx.y, k0 = kg * 4;
    const float thr = 0.75f * wsc[0] / (float)NW_;
    const float cnt = wsc[2];
    const float alpha = cnt > 0.f ? wsc[1] / fmaxf(cnt, 1.f) : 1.0f;
    for (int j = 0; j < 4; ++j) {
        const int sp = (int)threadIdx.x + j * 256;
        if (sp >= SP_) break;
        const int h = sp / W4_, w0 = (sp % W4_) * 4;
        float acc[4][4];
        #pragma unroll
        for (int kt = 0; kt < 4; ++kt)
            #pragma unroll
            for (int jj = 0; jj < 4; ++jj) acc[kt][jj] = 0.f;
        for (int c = 0; c < C_; ++c) {
            const float* xp = x + (((size_t)n * C_ + c) * H_) * W_;
            float xr[3][6];
            #pragma unroll
            for (int r = 0; r < 3; ++r) {
                const int hh = h + r - 1;
                const float* rowp = xp + hh * W_;
                if ((unsigned)hh < (unsigned)H_) {
                    const float4 mid = *(const float4*)(rowp + w0);
                    xr[r][1] = mid.x; xr[r][2] = mid.y; xr[r][3] = mid.z; xr[r][4] = mid.w;
                    xr[r][0] = (w0 > 0)      ? rowp[w0 - 1] : 0.f;
                    xr[r][5] = (w0 + 4 < W_) ? rowp[w0 + 4] : 0.f;
                } else {
                    #pragma unroll
                    for (int q = 0; q < 6; ++q) xr[r][q] = 0.f;
                }
            }
            #pragma unroll
            for (int kt = 0; kt < 4; ++kt) {
                const float* wp = wt + ((size_t)(k0 + kt) * C_ + c) * 9;
                #pragma unroll
                for (int r = 0; r < 3; ++r)
                    #pragma unroll
                    for (int s = 0; s < 3; ++s) {
                        float wv = wp[r * 3 + s];
                        wv = wv > thr ? alpha : (wv < -thr ? -alpha : 0.f);
                        #pragma unroll
                        for (int jj = 0; jj < 4; ++jj)
                            acc[kt][jj] = fmaf(wv, xr[r][jj + s], acc[kt][jj]);
                    }
            }
        }
        #pragma unroll
        for (int kt = 0; kt < 4; ++kt) {
            float4 o;
            o.x = acc[kt][0]; o.y = acc[kt][1]; o.z = acc[kt][2]; o.w = acc[kt][3];
            *(float4*)(out + ((((size_t)n * K_ + (k0 + kt)) * H_ + h) * W_ + w0)) = o;
        }
    }
}

extern "C" void kernel_launch(void* const* d_in, const int* in_sizes, int n_in,
                              void* d_out, int out_size, void* d_ws, size_t ws_size,
                              hipStream_t stream) {
    const float* x = (const float*)d_in[0];
    const float* w = (const float*)d_in[1];
    float* out = (float*)d_out;
    float* ws  = (float*)d_ws;
    unsigned short* wq = (unsigned short*)((char*)d_ws + WS_WQ);

    k_abs_partial<<<256, 256, 0, stream>>>(w, ws);
    k_masked_partial<<<256, 256, 0, stream>>>(w, ws);

    if (ws_size >= WS_NEEDED) {
        k_quant<<<(NW_ + 511) / 512, 512, 0, stream>>>(w, ws, wq);
        dim3 grid(NB, N_);
        conv_mfma<<<grid, 512, 0, stream>>>(x, wq, ws, out);
    } else {
        k_final_masked<<<1, 256, 0, stream>>>(ws);
        dim3 grid(64, N_);
        conv_tern_otf<<<grid, 256, 0, stream>>>(x, w, ws, out);
    }
}